// Round 2
// baseline (1668.240 us; speedup 1.0000x reference)
//
#include <hip/hip_runtime.h>

// Transformer block. fp32 in/out, bf16 MFMA internal, fp32 accumulation.
// DIM=768 HID=3072 HEADS=8 DEPTH=96 SEQ=128 GROUPS(B*F)=128 ROWS=16384

#define NROWS 16384
#define TDIM 768
#define THID 3072
#define EPS 1e-5f

typedef short bf16x8 __attribute__((ext_vector_type(8)));
typedef float f32x4 __attribute__((ext_vector_type(4)));

__device__ __forceinline__ float b2f(unsigned short u) {
    union { unsigned int i; float f; } v; v.i = ((unsigned int)u) << 16; return v.f;
}
__device__ __forceinline__ unsigned short f2b(float f) {
    union { float f; unsigned int i; } v; v.f = f;
    unsigned int r = v.i + 0x7fffu + ((v.i >> 16) & 1u);
    return (unsigned short)(r >> 16);
}

// ---------------- fp32 -> bf16 convert (weights), n divisible by 4
__global__ __launch_bounds__(256) void cvt_kernel(
    const float* __restrict__ src, unsigned short* __restrict__ dst, int n4)
{
    int i = blockIdx.x * 256 + threadIdx.x;
    if (i < n4) {
        float4 v = ((const float4*)src)[i];
        ushort4 o;
        o.x = f2b(v.x); o.y = f2b(v.y); o.z = f2b(v.z); o.w = f2b(v.w);
        ((ushort4*)dst)[i] = o;
    }
}

// ---------------- LayerNorm: one block per row, up to 3 tensors via blockIdx.y
// IN_F32: read fp32, else read bf16. Output always bf16.
template<bool IN_F32>
__global__ __launch_bounds__(256) void ln_kernel(
    const void* __restrict__ x0, const void* __restrict__ x1,
    const void* __restrict__ x2,
    const float* __restrict__ g, const float* __restrict__ bb,
    unsigned short* __restrict__ o0, unsigned short* __restrict__ o1,
    unsigned short* __restrict__ o2)
{
    int t = blockIdx.y;
    const void* x = (t == 0) ? x0 : (t == 1) ? x1 : x2;
    unsigned short* o = (t == 0) ? o0 : (t == 1) ? o1 : o2;
    size_t base = (size_t)blockIdx.x * TDIM;
    int tid = threadIdx.x;
    float v[3]; float sum = 0.f, sq = 0.f;
#pragma unroll
    for (int i = 0; i < 3; i++) {
        if constexpr (IN_F32) v[i] = ((const float*)x)[base + tid + i * 256];
        else v[i] = b2f(((const unsigned short*)x)[base + tid + i * 256]);
        sum += v[i]; sq += v[i] * v[i];
    }
#pragma unroll
    for (int o_ = 32; o_ > 0; o_ >>= 1) {
        sum += __shfl_down(sum, o_); sq += __shfl_down(sq, o_);
    }
    __shared__ float s1[4], s2[4];
    __shared__ float smu, srs;
    int wave = tid >> 6, lane = tid & 63;
    if (lane == 0) { s1[wave] = sum; s2[wave] = sq; }
    __syncthreads();
    if (tid == 0) {
        float S = s1[0] + s1[1] + s1[2] + s1[3];
        float Q = s2[0] + s2[1] + s2[2] + s2[3];
        float mu = S / (float)TDIM;
        float var = Q / (float)TDIM - mu * mu;
        smu = mu; srs = rsqrtf(var + EPS);
    }
    __syncthreads();
    float mu = smu, rs = srs;
#pragma unroll
    for (int i = 0; i < 3; i++) {
        int c = tid + i * 256;
        o[base + c] = f2b((v[i] - mu) * rs * g[c] + bb[c]);
    }
}

// ---------------- MFMA GEMM: C[M,N] = op(A@B (+bias) (+gelu) (+resid))
// A,B,resid bf16; bias fp32; C bf16 or fp32.
// 128x128 tile, BK=32, 256 threads = 4 waves, each wave 64x64 (4x4 of 16x16x32)
template<bool BIAS, bool RES, bool GELU, bool OUTF32>
__global__ __launch_bounds__(256) void gemm_kernel(
    const unsigned short* __restrict__ A, const unsigned short* __restrict__ B,
    const float* __restrict__ bias, const unsigned short* __restrict__ resid,
    void* __restrict__ Cv, int M, int N, int K)
{
    __shared__ unsigned short sA[128][40];  // [row][k], pad 8
    __shared__ unsigned short sB[128][40];  // transposed: [n][k], pad 8
    int tid = threadIdx.x;
    int row0 = blockIdx.y * 128;
    int col0 = blockIdx.x * 128;
    int wave = tid >> 6, lane = tid & 63;
    int wm = (wave >> 1) * 64, wn = (wave & 1) * 64;
    int cl = lane & 15, quad = lane >> 4;

    f32x4 acc[4][4];
#pragma unroll
    for (int i = 0; i < 4; i++)
#pragma unroll
        for (int j = 0; j < 4; j++) acc[i][j] = (f32x4){0.f, 0.f, 0.f, 0.f};

    for (int k0 = 0; k0 < K; k0 += 32) {
#pragma unroll
        for (int c = tid; c < 512; c += 256) {
            int r = c >> 2, kc = (c & 3) << 3;
            *(uint4*)(&sA[r][kc]) =
                *(const uint4*)(A + (size_t)(row0 + r) * K + k0 + kc);
        }
#pragma unroll
        for (int c = tid; c < 512; c += 256) {
            int kk = c >> 4, nc = (c & 15) << 3;
            uint4 t_ = *(const uint4*)(B + (size_t)(k0 + kk) * N + col0 + nc);
            unsigned short* tp = (unsigned short*)&t_;
#pragma unroll
            for (int j = 0; j < 8; j++) sB[nc + j][kk] = tp[j];
        }
        __syncthreads();
        bf16x8 af[4], bfr[4];
#pragma unroll
        for (int mi = 0; mi < 4; mi++)
            af[mi] = *(const bf16x8*)(&sA[wm + mi * 16 + cl][quad * 8]);
#pragma unroll
        for (int ni = 0; ni < 4; ni++)
            bfr[ni] = *(const bf16x8*)(&sB[wn + ni * 16 + cl][quad * 8]);
#pragma unroll
        for (int mi = 0; mi < 4; mi++)
#pragma unroll
            for (int ni = 0; ni < 4; ni++)
                acc[mi][ni] = __builtin_amdgcn_mfma_f32_16x16x32_bf16(
                    af[mi], bfr[ni], acc[mi][ni], 0, 0, 0);
        __syncthreads();
    }
    // epilogue: D[row][col] : col=lane&15, row=quad*4+r  (m89/m91-verified)
#pragma unroll
    for (int mi = 0; mi < 4; mi++) {
#pragma unroll
        for (int ni = 0; ni < 4; ni++) {
            int gc = col0 + wn + ni * 16 + cl;
            float bv = 0.f;
            if constexpr (BIAS) bv = bias[gc];
#pragma unroll
            for (int r = 0; r < 4; r++) {
                int gr = row0 + wm + mi * 16 + quad * 4 + r;
                float v = acc[mi][ni][r];
                if constexpr (BIAS) v += bv;
                if constexpr (GELU) {
                    float x = v;
                    v = 0.5f * x * (1.0f + tanhf(0.7978845608028654f *
                            (x + 0.044715f * x * x * x)));
                }
                if constexpr (RES) v += b2f(resid[(size_t)gr * N + gc]);
                size_t idx = (size_t)gr * N + gc;
                if constexpr (OUTF32) ((float*)Cv)[idx] = v;
                else ((unsigned short*)Cv)[idx] = f2b(v);
            }
        }
    }
}

// ---------------- Attention scores + softmax: one block per (b,f,h) head
// 512 threads: 4 threads per query row, 32 keys each. att output fp32.
__global__ __launch_bounds__(512) void attn_scores_kernel(
    const unsigned short* __restrict__ qh, const unsigned short* __restrict__ kh,
    float* __restrict__ att)
{
    __shared__ unsigned short sQ[128][104];  // 96+8 pad
    __shared__ unsigned short sK[128][104];
    int hb = blockIdx.x;
    int g = hb >> 3, h = hb & 7;
    int tid = threadIdx.x;
    size_t rbase = (size_t)g * 128 * TDIM + h * 96;
    for (int c = tid; c < 1536; c += 512) {
        int r = c / 12, dc = (c % 12) * 8;
        *(uint4*)(&sQ[r][dc]) = *(const uint4*)(qh + rbase + (size_t)r * TDIM + dc);
        *(uint4*)(&sK[r][dc]) = *(const uint4*)(kh + rbase + (size_t)r * TDIM + dc);
    }
    __syncthreads();
    int i = tid >> 2, j0 = (tid & 3) * 32;
    float s[32];
#pragma unroll
    for (int jj = 0; jj < 32; jj++) {
        float a = 0.f;
        for (int d = 0; d < 96; d++) a += b2f(sQ[i][d]) * b2f(sK[j0 + jj][d]);
        s[jj] = a * 0.10206207261596575f;  // 96^-0.5
    }
    float m = -1e30f;
#pragma unroll
    for (int jj = 0; jj < 32; jj++) m = fmaxf(m, s[jj]);
    m = fmaxf(m, __shfl_xor(m, 1));
    m = fmaxf(m, __shfl_xor(m, 2));
    float sum = 0.f;
#pragma unroll
    for (int jj = 0; jj < 32; jj++) { s[jj] = __expf(s[jj] - m); sum += s[jj]; }
    sum += __shfl_xor(sum, 1);
    sum += __shfl_xor(sum, 2);
    float inv = 1.0f / sum;
    size_t obase = ((size_t)hb * 128 + i) * 128 + j0;
#pragma unroll
    for (int jj = 0; jj < 32; jj++) att[obase + jj] = s[jj] * inv;
}

// ---------------- attout = P @ V per head. P fp32 global -> bf16 LDS.
__global__ __launch_bounds__(512) void attn_av_kernel(
    const float* __restrict__ att, const unsigned short* __restrict__ vh,
    unsigned short* __restrict__ attout)
{
    __shared__ unsigned short sP[128][136];  // 128+8 pad
    __shared__ unsigned short sV[128][104];  // 96+8 pad
    int hb = blockIdx.x, g = hb >> 3, h = hb & 7;
    int tid = threadIdx.x;
    size_t pbase = (size_t)hb * 128 * 128;
    for (int c = tid; c < 2048; c += 512) {
        int r = c >> 4, jc = (c & 15) * 8;
        float4 a0 = *(const float4*)(att + pbase + (size_t)r * 128 + jc);
        float4 a1 = *(const float4*)(att + pbase + (size_t)r * 128 + jc + 4);
        sP[r][jc + 0] = f2b(a0.x); sP[r][jc + 1] = f2b(a0.y);
        sP[r][jc + 2] = f2b(a0.z); sP[r][jc + 3] = f2b(a0.w);
        sP[r][jc + 4] = f2b(a1.x); sP[r][jc + 5] = f2b(a1.y);
        sP[r][jc + 6] = f2b(a1.z); sP[r][jc + 7] = f2b(a1.w);
    }
    size_t vbase = (size_t)g * 128 * TDIM + h * 96;
    for (int c = tid; c < 1536; c += 512) {
        int r = c / 12, dc = (c % 12) * 8;
        *(uint4*)(&sV[r][dc]) = *(const uint4*)(vh + vbase + (size_t)r * TDIM + dc);
    }
    __syncthreads();
    int i = tid >> 2, d0 = (tid & 3) * 24;
    float acc[24];
#pragma unroll
    for (int d = 0; d < 24; d++) acc[d] = 0.f;
    for (int j = 0; j < 128; j++) {
        float p = b2f(sP[i][j]);
#pragma unroll
        for (int d = 0; d < 24; d++) acc[d] += p * b2f(sV[j][d0 + d]);
    }
    size_t obase = vbase + (size_t)i * TDIM + d0;
#pragma unroll
    for (int d = 0; d < 24; d++) attout[obase + d] = f2b(acc[d]);
}

extern "C" void kernel_launch(void* const* d_in, const int* in_sizes, int n_in,
                              void* d_out, int out_size, void* d_ws, size_t ws_size,
                              hipStream_t stream)
{
    const float* q     = (const float*)d_in[0];
    const float* k     = (const float*)d_in[1];
    const float* v     = (const float*)d_in[2];
    const float* ln1_g = (const float*)d_in[3];
    const float* ln1_b = (const float*)d_in[4];
    const float* wq    = (const float*)d_in[5];
    const float* wk    = (const float*)d_in[6];
    const float* wv    = (const float*)d_in[7];
    const float* wo    = (const float*)d_in[8];
    const float* wo_b  = (const float*)d_in[9];
    const float* ln2_g = (const float*)d_in[10];
    const float* ln2_b = (const float*)d_in[11];
    const float* w1    = (const float*)d_in[12];
    const float* b1    = (const float*)d_in[13];
    const float* w2    = (const float*)d_in[14];
    const float* b2    = (const float*)d_in[15];

    float* out0 = (float*)d_out;
    const size_t S = (size_t)NROWS * TDIM;  // 12,582,912
    float* att = out0 + S;                  // output 1: (2,64,8,128,128) fp32
    unsigned short* ws = (unsigned short*)d_ws;
    if (ws_size < 7 * S * sizeof(unsigned short)) return;  // need ~168 MB

    const int W = TDIM * TDIM;       // 589,824
    const int W2 = TDIM * THID;      // 2,359,296

    // ws slots (each S bf16 elements):
    unsigned short* qn     = ws;          // slot0; later ln2y
    unsigned short* kn     = ws + S;      // slot1; later attout, then w1b/w2b
    unsigned short* vn     = ws + 2 * S;  // slot2; later y
    unsigned short* qh     = ws + 3 * S;  // slot3..5: qh/kh/vh; later hbuf (3..6)
    unsigned short* kh     = ws + 4 * S;
    unsigned short* vh     = ws + 5 * S;
    unsigned short* wqkvo  = ws + 6 * S;  // slot6: wq/wk/wv/wo bf16 (dead before hbuf)
    unsigned short* attout = ws + S;
    unsigned short* y      = ws + 2 * S;
    unsigned short* ln2y   = ws;
    unsigned short* w1b    = ws + S;          // after attout is dead
    unsigned short* w2b    = ws + S + W2;
    unsigned short* hbuf   = ws + 3 * S;      // 16384 x 3072 (4S)

    dim3 blk(256);
    // 0. convert attention weights to bf16 (into slot6, dead before hbuf)
    cvt_kernel<<<dim3(W / 1024), blk, 0, stream>>>(wq, wqkvo + 0 * (size_t)W, W / 4);
    cvt_kernel<<<dim3(W / 1024), blk, 0, stream>>>(wk, wqkvo + 1 * (size_t)W, W / 4);
    cvt_kernel<<<dim3(W / 1024), blk, 0, stream>>>(wv, wqkvo + 2 * (size_t)W, W / 4);
    cvt_kernel<<<dim3(W / 1024), blk, 0, stream>>>(wo, wqkvo + 3 * (size_t)W, W / 4);
    // 1. LayerNorm1 on q,k,v (fp32 in, bf16 out)
    ln_kernel<true><<<dim3(NROWS, 3), blk, 0, stream>>>(
        q, k, v, ln1_g, ln1_b, qn, kn, vn);
    // 2. projections
    gemm_kernel<false, false, false, false><<<dim3(6, 128), blk, 0, stream>>>(
        qn, wqkvo + 0 * (size_t)W, nullptr, nullptr, qh, NROWS, TDIM, TDIM);
    gemm_kernel<false, false, false, false><<<dim3(6, 128), blk, 0, stream>>>(
        kn, wqkvo + 1 * (size_t)W, nullptr, nullptr, kh, NROWS, TDIM, TDIM);
    gemm_kernel<false, false, false, false><<<dim3(6, 128), blk, 0, stream>>>(
        vn, wqkvo + 2 * (size_t)W, nullptr, nullptr, vh, NROWS, TDIM, TDIM);
    // 3. attention
    attn_scores_kernel<<<dim3(1024), dim3(512), 0, stream>>>(qh, kh, att);
    attn_av_kernel<<<dim3(1024), dim3(512), 0, stream>>>(att, vh, attout);
    // 4. output proj + bias + residual(qn) -> y (bf16)
    gemm_kernel<true, true, false, false><<<dim3(6, 128), blk, 0, stream>>>(
        attout, wqkvo + 3 * (size_t)W, wo_b, qn, y, NROWS, TDIM, TDIM);
    // 4b. convert FFN weights (into slot1, attout now dead)
    cvt_kernel<<<dim3(W2 / 1024), blk, 0, stream>>>(w1, w1b, W2 / 4);
    cvt_kernel<<<dim3(W2 / 1024), blk, 0, stream>>>(w2, w2b, W2 / 4);
    // 5. LayerNorm2 (bf16 in, bf16 out)
    ln_kernel<false><<<dim3(NROWS, 1), blk, 0, stream>>>(
        y, y, y, ln2_g, ln2_b, ln2y, ln2y, ln2y);
    // 6. FFN
    gemm_kernel<true, false, true, false><<<dim3(24, 128), blk, 0, stream>>>(
        ln2y, w1b, b1, nullptr, hbuf, NROWS, THID, TDIM);
    gemm_kernel<true, true, false, true><<<dim3(6, 128), blk, 0, stream>>>(
        hbuf, w2b, b2, y, out0, NROWS, TDIM, THID);
}

// Round 3
// 1014.396 us; speedup vs baseline: 1.6446x; 1.6446x over previous
//
#include <hip/hip_runtime.h>

// Transformer block. fp32 in/out, bf16 MFMA internal, fp32 accumulation.
// DIM=768 HID=3072 HEADS=8 DEPTH=96 SEQ=128 GROUPS(B*F)=128 ROWS=16384
// R3: m97-style GEMM — pre-transposed weights (B^T[n][k]) + global_load_lds
//     width-16 staging into unpadded LDS tiles. Kills the 1.56e8 LDS bank
//     conflicts from the R2 in-kernel software transpose.

#define NROWS 16384
#define TDIM 768
#define THID 3072
#define EPS 1e-5f

typedef short bf16x8 __attribute__((ext_vector_type(8)));
typedef float f32x4 __attribute__((ext_vector_type(4)));

__device__ __forceinline__ float b2f(unsigned short u) {
    union { unsigned int i; float f; } v; v.i = ((unsigned int)u) << 16; return v.f;
}
__device__ __forceinline__ unsigned short f2b(float f) {
    union { float f; unsigned int i; } v; v.f = f;
    unsigned int r = v.i + 0x7fffu + ((v.i >> 16) & 1u);
    return (unsigned short)(r >> 16);
}

// async 16B global -> LDS (lds dest must be wave-uniform base; HW adds lane*16)
__device__ __forceinline__ void async_copy16(const unsigned short* g, unsigned short* l) {
    __builtin_amdgcn_global_load_lds(
        (const __attribute__((address_space(1))) unsigned int*)g,
        (__attribute__((address_space(3))) unsigned int*)l,
        16, 0, 0);
}

// ---------------- fp32 [K][N] -> bf16 transposed [N][K]
__global__ __launch_bounds__(256) void cvt_t_kernel(
    const float* __restrict__ src, unsigned short* __restrict__ dst, int K, int N)
{
    __shared__ unsigned short tile[32][33];
    int n0 = blockIdx.x * 32, k0 = blockIdx.y * 32;
    int tx = threadIdx.x & 31, ty = threadIdx.x >> 5;  // ty in 0..7
#pragma unroll
    for (int r = ty; r < 32; r += 8)
        tile[r][tx] = f2b(src[(size_t)(k0 + r) * N + n0 + tx]);
    __syncthreads();
#pragma unroll
    for (int r = ty; r < 32; r += 8)
        dst[(size_t)(n0 + r) * K + k0 + tx] = tile[tx][r];
}

// ---------------- LayerNorm: one block per row, up to 3 tensors via blockIdx.y
template<bool IN_F32>
__global__ __launch_bounds__(256) void ln_kernel(
    const void* __restrict__ x0, const void* __restrict__ x1,
    const void* __restrict__ x2,
    const float* __restrict__ g, const float* __restrict__ bb,
    unsigned short* __restrict__ o0, unsigned short* __restrict__ o1,
    unsigned short* __restrict__ o2)
{
    int t = blockIdx.y;
    const void* x = (t == 0) ? x0 : (t == 1) ? x1 : x2;
    unsigned short* o = (t == 0) ? o0 : (t == 1) ? o1 : o2;
    size_t base = (size_t)blockIdx.x * TDIM;
    int tid = threadIdx.x;
    float v[3]; float sum = 0.f, sq = 0.f;
#pragma unroll
    for (int i = 0; i < 3; i++) {
        if constexpr (IN_F32) v[i] = ((const float*)x)[base + tid + i * 256];
        else v[i] = b2f(((const unsigned short*)x)[base + tid + i * 256]);
        sum += v[i]; sq += v[i] * v[i];
    }
#pragma unroll
    for (int o_ = 32; o_ > 0; o_ >>= 1) {
        sum += __shfl_down(sum, o_); sq += __shfl_down(sq, o_);
    }
    __shared__ float s1[4], s2[4];
    __shared__ float smu, srs;
    int wave = tid >> 6, lane = tid & 63;
    if (lane == 0) { s1[wave] = sum; s2[wave] = sq; }
    __syncthreads();
    if (tid == 0) {
        float S = s1[0] + s1[1] + s1[2] + s1[3];
        float Q = s2[0] + s2[1] + s2[2] + s2[3];
        float mu = S / (float)TDIM;
        float var = Q / (float)TDIM - mu * mu;
        smu = mu; srs = rsqrtf(var + EPS);
    }
    __syncthreads();
    float mu = smu, rs = srs;
#pragma unroll
    for (int i = 0; i < 3; i++) {
        int c = tid + i * 256;
        o[base + c] = f2b((v[i] - mu) * rs * g[c] + bb[c]);
    }
}

// ---------------- MFMA GEMM: C[M,N] = op(A[M,K] @ BT[N,K]^T (+bias)(+gelu)(+res))
// 128x128 tile, BK=32, 4 waves, each wave 64x64 (4x4 of 16x16x32).
// Staging via global_load_lds width-16; LDS unpadded (required by the HW
// wave-uniform-base + lane*16 dest rule).
template<bool BIAS, bool RES, bool GELU, bool OUTF32>
__global__ __launch_bounds__(256) void gemm_kernel(
    const unsigned short* __restrict__ A, const unsigned short* __restrict__ BT,
    const float* __restrict__ bias, const unsigned short* __restrict__ resid,
    void* __restrict__ Cv, int M, int N, int K)
{
    __shared__ unsigned short sA[128][32];  // [row][k]  8 KB
    __shared__ unsigned short sB[128][32];  // [n][k]    8 KB
    int tid = threadIdx.x;
    int row0 = blockIdx.y * 128;
    int col0 = blockIdx.x * 128;
    int wave = tid >> 6, lane = tid & 63;
    int wm = (wave >> 1) * 64, wn = (wave & 1) * 64;
    int cl = lane & 15, quad = lane >> 4;

    f32x4 acc[4][4];
#pragma unroll
    for (int i = 0; i < 4; i++)
#pragma unroll
        for (int j = 0; j < 4; j++) acc[i][j] = (f32x4){0.f, 0.f, 0.f, 0.f};

    const unsigned short* Arow = A + (size_t)row0 * K;
    const unsigned short* Brow = BT + (size_t)col0 * K;

    for (int k0 = 0; k0 < K; k0 += 32) {
        // stage A,B: 512 chunks of 16B each; wave w issues chunks
        // [w*128 + i*64 + lane]; LDS dest = uniform base, HW adds lane*16.
#pragma unroll
        for (int i = 0; i < 2; i++) {
            int cb = wave * 128 + i * 64;
            int c = cb + lane;
            int r = c >> 2, kc = (c & 3) << 3;
            async_copy16(Arow + (size_t)r * K + k0 + kc, &sA[0][0] + cb * 8);
            async_copy16(Brow + (size_t)r * K + k0 + kc, &sB[0][0] + cb * 8);
        }
        __syncthreads();
        bf16x8 af[4], bfr[4];
#pragma unroll
        for (int mi = 0; mi < 4; mi++)
            af[mi] = *(const bf16x8*)(&sA[wm + mi * 16 + cl][quad * 8]);
#pragma unroll
        for (int ni = 0; ni < 4; ni++)
            bfr[ni] = *(const bf16x8*)(&sB[wn + ni * 16 + cl][quad * 8]);
#pragma unroll
        for (int mi = 0; mi < 4; mi++)
#pragma unroll
            for (int ni = 0; ni < 4; ni++)
                acc[mi][ni] = __builtin_amdgcn_mfma_f32_16x16x32_bf16(
                    af[mi], bfr[ni], acc[mi][ni], 0, 0, 0);
        __syncthreads();
    }
    // epilogue: D[row][col] : col=lane&15, row=quad*4+r  (m89/m91-verified)
#pragma unroll
    for (int mi = 0; mi < 4; mi++) {
#pragma unroll
        for (int ni = 0; ni < 4; ni++) {
            int gc = col0 + wn + ni * 16 + cl;
            float bv = 0.f;
            if constexpr (BIAS) bv = bias[gc];
#pragma unroll
            for (int r = 0; r < 4; r++) {
                int gr = row0 + wm + mi * 16 + quad * 4 + r;
                float v = acc[mi][ni][r];
                if constexpr (BIAS) v += bv;
                if constexpr (GELU) {
                    float x = v;
                    v = 0.5f * x * (1.0f + tanhf(0.7978845608028654f *
                            (x + 0.044715f * x * x * x)));
                }
                if constexpr (RES) v += b2f(resid[(size_t)gr * N + gc]);
                size_t idx = (size_t)gr * N + gc;
                if constexpr (OUTF32) ((float*)Cv)[idx] = v;
                else ((unsigned short*)Cv)[idx] = f2b(v);
            }
        }
    }
}

// ---------------- Attention scores + softmax: one block per (b,f,h) head
__global__ __launch_bounds__(512) void attn_scores_kernel(
    const unsigned short* __restrict__ qh, const unsigned short* __restrict__ kh,
    float* __restrict__ att)
{
    __shared__ unsigned short sQ[128][104];  // 96+8 pad
    __shared__ unsigned short sK[128][104];
    int hb = blockIdx.x;
    int g = hb >> 3, h = hb & 7;
    int tid = threadIdx.x;
    size_t rbase = (size_t)g * 128 * TDIM + h * 96;
    for (int c = tid; c < 1536; c += 512) {
        int r = c / 12, dc = (c % 12) * 8;
        *(uint4*)(&sQ[r][dc]) = *(const uint4*)(qh + rbase + (size_t)r * TDIM + dc);
        *(uint4*)(&sK[r][dc]) = *(const uint4*)(kh + rbase + (size_t)r * TDIM + dc);
    }
    __syncthreads();
    int i = tid >> 2, j0 = (tid & 3) * 32;
    float s[32];
#pragma unroll
    for (int jj = 0; jj < 32; jj++) {
        float a = 0.f;
        for (int d = 0; d < 96; d++) a += b2f(sQ[i][d]) * b2f(sK[j0 + jj][d]);
        s[jj] = a * 0.10206207261596575f;  // 96^-0.5
    }
    float m = -1e30f;
#pragma unroll
    for (int jj = 0; jj < 32; jj++) m = fmaxf(m, s[jj]);
    m = fmaxf(m, __shfl_xor(m, 1));
    m = fmaxf(m, __shfl_xor(m, 2));
    float sum = 0.f;
#pragma unroll
    for (int jj = 0; jj < 32; jj++) { s[jj] = __expf(s[jj] - m); sum += s[jj]; }
    sum += __shfl_xor(sum, 1);
    sum += __shfl_xor(sum, 2);
    float inv = 1.0f / sum;
    size_t obase = ((size_t)hb * 128 + i) * 128 + j0;
#pragma unroll
    for (int jj = 0; jj < 32; jj++) att[obase + jj] = s[jj] * inv;
}

// ---------------- attout = P @ V per head. P fp32 global -> bf16 LDS.
__global__ __launch_bounds__(512) void attn_av_kernel(
    const float* __restrict__ att, const unsigned short* __restrict__ vh,
    unsigned short* __restrict__ attout)
{
    __shared__ unsigned short sP[128][136];  // 128+8 pad
    __shared__ unsigned short sV[128][104];  // 96+8 pad
    int hb = blockIdx.x, g = hb >> 3, h = hb & 7;
    int tid = threadIdx.x;
    size_t pbase = (size_t)hb * 128 * 128;
    for (int c = tid; c < 2048; c += 512) {
        int r = c >> 4, jc = (c & 15) * 8;
        float4 a0 = *(const float4*)(att + pbase + (size_t)r * 128 + jc);
        float4 a1 = *(const float4*)(att + pbase + (size_t)r * 128 + jc + 4);
        sP[r][jc + 0] = f2b(a0.x); sP[r][jc + 1] = f2b(a0.y);
        sP[r][jc + 2] = f2b(a0.z); sP[r][jc + 3] = f2b(a0.w);
        sP[r][jc + 4] = f2b(a1.x); sP[r][jc + 5] = f2b(a1.y);
        sP[r][jc + 6] = f2b(a1.z); sP[r][jc + 7] = f2b(a1.w);
    }
    size_t vbase = (size_t)g * 128 * TDIM + h * 96;
    for (int c = tid; c < 1536; c += 512) {
        int r = c / 12, dc = (c % 12) * 8;
        *(uint4*)(&sV[r][dc]) = *(const uint4*)(vh + vbase + (size_t)r * TDIM + dc);
    }
    __syncthreads();
    int i = tid >> 2, d0 = (tid & 3) * 24;
    float acc[24];
#pragma unroll
    for (int d = 0; d < 24; d++) acc[d] = 0.f;
    for (int j = 0; j < 128; j++) {
        float p = b2f(sP[i][j]);
#pragma unroll
        for (int d = 0; d < 24; d++) acc[d] += p * b2f(sV[j][d0 + d]);
    }
    size_t obase = vbase + (size_t)i * TDIM + d0;
#pragma unroll
    for (int d = 0; d < 24; d++) attout[obase + d] = f2b(acc[d]);
}

extern "C" void kernel_launch(void* const* d_in, const int* in_sizes, int n_in,
                              void* d_out, int out_size, void* d_ws, size_t ws_size,
                              hipStream_t stream)
{
    const float* q     = (const float*)d_in[0];
    const float* k     = (const float*)d_in[1];
    const float* v     = (const float*)d_in[2];
    const float* ln1_g = (const float*)d_in[3];
    const float* ln1_b = (const float*)d_in[4];
    const float* wq    = (const float*)d_in[5];
    const float* wk    = (const float*)d_in[6];
    const float* wv    = (const float*)d_in[7];
    const float* wo    = (const float*)d_in[8];
    const float* wo_b  = (const float*)d_in[9];
    const float* ln2_g = (const float*)d_in[10];
    const float* ln2_b = (const float*)d_in[11];
    const float* w1    = (const float*)d_in[12];
    const float* b1    = (const float*)d_in[13];
    const float* w2    = (const float*)d_in[14];
    const float* b2    = (const float*)d_in[15];

    float* out0 = (float*)d_out;
    const size_t S = (size_t)NROWS * TDIM;  // 12,582,912
    float* att = out0 + S;                  // output 1: (2,64,8,128,128) fp32
    unsigned short* ws = (unsigned short*)d_ws;
    if (ws_size < 7 * S * sizeof(unsigned short)) return;  // need ~168 MB

    const size_t W = (size_t)TDIM * TDIM;   // 589,824
    const size_t W2 = (size_t)TDIM * THID;  // 2,359,296

    // ws slots (each S bf16 elements):
    unsigned short* qn     = ws;          // slot0; later ln2y
    unsigned short* kn     = ws + S;      // slot1; later attout, then w1T/w2T
    unsigned short* vn     = ws + 2 * S;  // slot2; later y
    unsigned short* qh     = ws + 3 * S;  // slot3..5: qh/kh/vh; later hbuf (3..6)
    unsigned short* kh     = ws + 4 * S;
    unsigned short* vh     = ws + 5 * S;
    unsigned short* wqkvoT = ws + 6 * S;  // slot6: wq/wk/wv/wo ^T bf16 (dead at ffn1)
    unsigned short* attout = ws + S;
    unsigned short* y      = ws + 2 * S;
    unsigned short* ln2y   = ws;
    unsigned short* w1T    = ws + S;      // [3072][768], after attout dead
    unsigned short* w2T    = ws + S + W2; // [768][3072]
    unsigned short* hbuf   = ws + 3 * S;  // 16384 x 3072 (4S)

    dim3 blk(256);
    // 0. transpose+convert attention weights to bf16 B^T
    cvt_t_kernel<<<dim3(24, 24), blk, 0, stream>>>(wq, wqkvoT + 0 * W, TDIM, TDIM);
    cvt_t_kernel<<<dim3(24, 24), blk, 0, stream>>>(wk, wqkvoT + 1 * W, TDIM, TDIM);
    cvt_t_kernel<<<dim3(24, 24), blk, 0, stream>>>(wv, wqkvoT + 2 * W, TDIM, TDIM);
    cvt_t_kernel<<<dim3(24, 24), blk, 0, stream>>>(wo, wqkvoT + 3 * W, TDIM, TDIM);
    // 1. LayerNorm1 on q,k,v (fp32 in, bf16 out)
    ln_kernel<true><<<dim3(NROWS, 3), blk, 0, stream>>>(
        q, k, v, ln1_g, ln1_b, qn, kn, vn);
    // 2. projections
    gemm_kernel<false, false, false, false><<<dim3(6, 128), blk, 0, stream>>>(
        qn, wqkvoT + 0 * W, nullptr, nullptr, qh, NROWS, TDIM, TDIM);
    gemm_kernel<false, false, false, false><<<dim3(6, 128), blk, 0, stream>>>(
        kn, wqkvoT + 1 * W, nullptr, nullptr, kh, NROWS, TDIM, TDIM);
    gemm_kernel<false, false, false, false><<<dim3(6, 128), blk, 0, stream>>>(
        vn, wqkvoT + 2 * W, nullptr, nullptr, vh, NROWS, TDIM, TDIM);
    // 3. attention
    attn_scores_kernel<<<dim3(1024), dim3(512), 0, stream>>>(qh, kh, att);
    attn_av_kernel<<<dim3(1024), dim3(512), 0, stream>>>(att, vh, attout);
    // 4. output proj + bias + residual(qn) -> y (bf16)
    gemm_kernel<true, true, false, false><<<dim3(6, 128), blk, 0, stream>>>(
        attout, wqkvoT + 3 * W, wo_b, qn, y, NROWS, TDIM, TDIM);
    // 4b. transpose+convert FFN weights (into slot1, attout now dead)
    cvt_t_kernel<<<dim3(96, 24), blk, 0, stream>>>(w1, w1T, TDIM, THID);
    cvt_t_kernel<<<dim3(24, 96), blk, 0, stream>>>(w2, w2T, THID, TDIM);
    // 5. LayerNorm2 (bf16 in, bf16 out)
    ln_kernel<false><<<dim3(NROWS, 1), blk, 0, stream>>>(
        y, y, y, ln2_g, ln2_b, ln2y, ln2y, ln2y);
    // 6. FFN
    gemm_kernel<true, false, true, false><<<dim3(24, 128), blk, 0, stream>>>(
        ln2y, w1T, b1, nullptr, hbuf, NROWS, THID, TDIM);
    gemm_kernel<true, true, false, true><<<dim3(6, 128), blk, 0, stream>>>(
        hbuf, w2T, b2, y, out0, NROWS, TDIM, THID);
}

// Round 4
// 795.417 us; speedup vs baseline: 2.0973x; 1.2753x over previous
//
#include <hip/hip_runtime.h>

// Transformer block. fp32 in/out, bf16 MFMA internal, fp32 accumulation.
// DIM=768 HID=3072 HEADS=8 DEPTH=96 SEQ=128 GROUPS(B*F)=128 ROWS=16384
// R4: fused MFMA attention (QK^T -> softmax -> PV in one kernel per head).
//     R3's scalar-VALU attn kernels (209+~150 us, MfmaUtil=0) replaced.

#define NROWS 16384
#define TDIM 768
#define THID 3072
#define EPS 1e-5f

typedef short bf16x8 __attribute__((ext_vector_type(8)));
typedef float f32x4 __attribute__((ext_vector_type(4)));

__device__ __forceinline__ float b2f(unsigned short u) {
    union { unsigned int i; float f; } v; v.i = ((unsigned int)u) << 16; return v.f;
}
__device__ __forceinline__ unsigned short f2b(float f) {
    union { float f; unsigned int i; } v; v.f = f;
    unsigned int r = v.i + 0x7fffu + ((v.i >> 16) & 1u);
    return (unsigned short)(r >> 16);
}

// async 16B global -> LDS (lds dest is wave-uniform base; HW adds lane*16)
__device__ __forceinline__ void async_copy16(const unsigned short* g, unsigned short* l) {
    __builtin_amdgcn_global_load_lds(
        (const __attribute__((address_space(1))) unsigned int*)g,
        (__attribute__((address_space(3))) unsigned int*)l,
        16, 0, 0);
}

// ---------------- fp32 [K][N] -> bf16 transposed [N][K]
__global__ __launch_bounds__(256) void cvt_t_kernel(
    const float* __restrict__ src, unsigned short* __restrict__ dst, int K, int N)
{
    __shared__ unsigned short tile[32][33];
    int n0 = blockIdx.x * 32, k0 = blockIdx.y * 32;
    int tx = threadIdx.x & 31, ty = threadIdx.x >> 5;
#pragma unroll
    for (int r = ty; r < 32; r += 8)
        tile[r][tx] = f2b(src[(size_t)(k0 + r) * N + n0 + tx]);
    __syncthreads();
#pragma unroll
    for (int r = ty; r < 32; r += 8)
        dst[(size_t)(n0 + r) * K + k0 + tx] = tile[tx][r];
}

// ---------------- LayerNorm: one block per row, up to 3 tensors via blockIdx.y
template<bool IN_F32>
__global__ __launch_bounds__(256) void ln_kernel(
    const void* __restrict__ x0, const void* __restrict__ x1,
    const void* __restrict__ x2,
    const float* __restrict__ g, const float* __restrict__ bb,
    unsigned short* __restrict__ o0, unsigned short* __restrict__ o1,
    unsigned short* __restrict__ o2)
{
    int t = blockIdx.y;
    const void* x = (t == 0) ? x0 : (t == 1) ? x1 : x2;
    unsigned short* o = (t == 0) ? o0 : (t == 1) ? o1 : o2;
    size_t base = (size_t)blockIdx.x * TDIM;
    int tid = threadIdx.x;
    float v[3]; float sum = 0.f, sq = 0.f;
#pragma unroll
    for (int i = 0; i < 3; i++) {
        if constexpr (IN_F32) v[i] = ((const float*)x)[base + tid + i * 256];
        else v[i] = b2f(((const unsigned short*)x)[base + tid + i * 256]);
        sum += v[i]; sq += v[i] * v[i];
    }
#pragma unroll
    for (int o_ = 32; o_ > 0; o_ >>= 1) {
        sum += __shfl_down(sum, o_); sq += __shfl_down(sq, o_);
    }
    __shared__ float s1[4], s2[4];
    __shared__ float smu, srs;
    int wave = tid >> 6, lane = tid & 63;
    if (lane == 0) { s1[wave] = sum; s2[wave] = sq; }
    __syncthreads();
    if (tid == 0) {
        float S = s1[0] + s1[1] + s1[2] + s1[3];
        float Q = s2[0] + s2[1] + s2[2] + s2[3];
        float mu = S / (float)TDIM;
        float var = Q / (float)TDIM - mu * mu;
        smu = mu; srs = rsqrtf(var + EPS);
    }
    __syncthreads();
    float mu = smu, rs = srs;
#pragma unroll
    for (int i = 0; i < 3; i++) {
        int c = tid + i * 256;
        o[base + c] = f2b((v[i] - mu) * rs * g[c] + bb[c]);
    }
}

// ---------------- MFMA GEMM: C[M,N] = op(A[M,K] @ BT[N,K]^T (+bias)(+gelu)(+res))
template<bool BIAS, bool RES, bool GELU, bool OUTF32>
__global__ __launch_bounds__(256) void gemm_kernel(
    const unsigned short* __restrict__ A, const unsigned short* __restrict__ BT,
    const float* __restrict__ bias, const unsigned short* __restrict__ resid,
    void* __restrict__ Cv, int M, int N, int K)
{
    __shared__ unsigned short sA[128][32];
    __shared__ unsigned short sB[128][32];
    int tid = threadIdx.x;
    int row0 = blockIdx.y * 128;
    int col0 = blockIdx.x * 128;
    int wave = tid >> 6, lane = tid & 63;
    int wm = (wave >> 1) * 64, wn = (wave & 1) * 64;
    int cl = lane & 15, quad = lane >> 4;

    f32x4 acc[4][4];
#pragma unroll
    for (int i = 0; i < 4; i++)
#pragma unroll
        for (int j = 0; j < 4; j++) acc[i][j] = (f32x4){0.f, 0.f, 0.f, 0.f};

    const unsigned short* Arow = A + (size_t)row0 * K;
    const unsigned short* Brow = BT + (size_t)col0 * K;

    for (int k0 = 0; k0 < K; k0 += 32) {
#pragma unroll
        for (int i = 0; i < 2; i++) {
            int cb = wave * 128 + i * 64;
            int c = cb + lane;
            int r = c >> 2, kc = (c & 3) << 3;
            async_copy16(Arow + (size_t)r * K + k0 + kc, &sA[0][0] + cb * 8);
            async_copy16(Brow + (size_t)r * K + k0 + kc, &sB[0][0] + cb * 8);
        }
        __syncthreads();
        bf16x8 af[4], bfr[4];
#pragma unroll
        for (int mi = 0; mi < 4; mi++)
            af[mi] = *(const bf16x8*)(&sA[wm + mi * 16 + cl][quad * 8]);
#pragma unroll
        for (int ni = 0; ni < 4; ni++)
            bfr[ni] = *(const bf16x8*)(&sB[wn + ni * 16 + cl][quad * 8]);
#pragma unroll
        for (int mi = 0; mi < 4; mi++)
#pragma unroll
            for (int ni = 0; ni < 4; ni++)
                acc[mi][ni] = __builtin_amdgcn_mfma_f32_16x16x32_bf16(
                    af[mi], bfr[ni], acc[mi][ni], 0, 0, 0);
        __syncthreads();
    }
#pragma unroll
    for (int mi = 0; mi < 4; mi++) {
#pragma unroll
        for (int ni = 0; ni < 4; ni++) {
            int gc = col0 + wn + ni * 16 + cl;
            float bv = 0.f;
            if constexpr (BIAS) bv = bias[gc];
#pragma unroll
            for (int r = 0; r < 4; r++) {
                int gr = row0 + wm + mi * 16 + quad * 4 + r;
                float v = acc[mi][ni][r];
                if constexpr (BIAS) v += bv;
                if constexpr (GELU) {
                    float x = v;
                    v = 0.5f * x * (1.0f + tanhf(0.7978845608028654f *
                            (x + 0.044715f * x * x * x)));
                }
                if constexpr (RES) v += b2f(resid[(size_t)gr * N + gc]);
                size_t idx = (size_t)gr * N + gc;
                if constexpr (OUTF32) ((float*)Cv)[idx] = v;
                else ((unsigned short*)Cv)[idx] = f2b(v);
            }
        }
    }
}

// ---------------- Fused attention: per-head QK^T -> softmax -> att + PV
// Block = 256 threads (4 waves), grid = 1024 heads.
// Phase1: S(128x128) via MFMA, wave quadrants 64x64.
// Softmax: register rows + 16-lane shfl + LDS exchange across wave pair.
// Phase2: O = P(128x128) @ V(128x96) via MFMA, wave = 32 rows x 96 cols.
__global__ __launch_bounds__(256) void attn_fused_kernel(
    const unsigned short* __restrict__ qh, const unsigned short* __restrict__ kh,
    const unsigned short* __restrict__ vh, float* __restrict__ att,
    unsigned short* __restrict__ attout)
{
    __shared__ __align__(16) unsigned short smem[30464];
    __shared__ float wmax[2][128];
    __shared__ float wsum[2][128];
    __shared__ float sInv[128];
    // phase1 aliases: sQ = smem[0..12287] [128][96], sK = smem[12288..] [128][96]
    // phase2 aliases: sP = smem[0..17407] [128][136], sVt = smem[17408..] [96][136]
    unsigned short* sQ = smem;
    unsigned short* sK = smem + 12288;
    unsigned short* sP = smem;
    unsigned short* sVt = smem + 17408;

    int hb = blockIdx.x, g = hb >> 3, h = hb & 7;
    int tid = threadIdx.x;
    int wave = tid >> 6, lane = tid & 63;
    int cl = lane & 15, quad = lane >> 4;
    int wm = (wave >> 1) * 64, wn = (wave & 1) * 64;

    size_t rbase = (size_t)g * 128 * TDIM + (size_t)h * 96;

    // ---- stage Q,K: 1536 16B-chunks each; chunk c -> LDS offset c*16B (linear)
#pragma unroll
    for (int it = 0; it < 6; it++) {
        int cb = wave * 384 + it * 64;
        int c = cb + lane;
        int r = c / 12, dc = (c % 12) * 8;
        async_copy16(qh + rbase + (size_t)r * TDIM + dc, sQ + (size_t)cb * 8);
        async_copy16(kh + rbase + (size_t)r * TDIM + dc, sK + (size_t)cb * 8);
    }
    __syncthreads();

    // ---- Phase 1: S = Q @ K^T (wave quadrant 64x64), K-dim 96 = 3 steps
    f32x4 acc[4][4];
#pragma unroll
    for (int i = 0; i < 4; i++)
#pragma unroll
        for (int j = 0; j < 4; j++) acc[i][j] = (f32x4){0.f, 0.f, 0.f, 0.f};
#pragma unroll
    for (int kk = 0; kk < 3; kk++) {
        bf16x8 af[4], bfr[4];
#pragma unroll
        for (int mi = 0; mi < 4; mi++)
            af[mi] = *(const bf16x8*)(sQ + (size_t)(wm + mi * 16 + cl) * 96 + kk * 32 + quad * 8);
#pragma unroll
        for (int ni = 0; ni < 4; ni++)
            bfr[ni] = *(const bf16x8*)(sK + (size_t)(wn + ni * 16 + cl) * 96 + kk * 32 + quad * 8);
#pragma unroll
        for (int mi = 0; mi < 4; mi++)
#pragma unroll
            for (int ni = 0; ni < 4; ni++)
                acc[mi][ni] = __builtin_amdgcn_mfma_f32_16x16x32_bf16(
                    af[mi], bfr[ni], acc[mi][ni], 0, 0, 0);
    }

    // ---- scale + row max (C layout: col=cl, row=quad*4+r within frag)
    const float scale = 0.10206207261596575f;  // 96^-0.5
#pragma unroll
    for (int mi = 0; mi < 4; mi++)
#pragma unroll
        for (int ni = 0; ni < 4; ni++)
#pragma unroll
            for (int r = 0; r < 4; r++) acc[mi][ni][r] *= scale;
#pragma unroll
    for (int mi = 0; mi < 4; mi++) {
#pragma unroll
        for (int r = 0; r < 4; r++) {
            float m = fmaxf(fmaxf(acc[mi][0][r], acc[mi][1][r]),
                            fmaxf(acc[mi][2][r], acc[mi][3][r]));
            m = fmaxf(m, __shfl_xor(m, 1));
            m = fmaxf(m, __shfl_xor(m, 2));
            m = fmaxf(m, __shfl_xor(m, 4));
            m = fmaxf(m, __shfl_xor(m, 8));
            if (cl == 0) wmax[wn >> 6][wm + mi * 16 + quad * 4 + r] = m;
        }
    }
    __syncthreads();  // b1: wmax ready; sQ/sK dead from here

    // ---- stage V^T into sVt[96][136] (staggered j to spread banks)
    for (int c = tid; c < 1536; c += 256) {
        int kk2 = c / 12, dc2 = (c % 12) * 8;
        uint4 t_ = *(const uint4*)(vh + rbase + (size_t)kk2 * TDIM + dc2);
        unsigned short* tp = (unsigned short*)&t_;
#pragma unroll
        for (int j = 0; j < 8; j++) {
            int jj = (j + tid) & 7;
            sVt[(size_t)(dc2 + jj) * 136 + kk2] = tp[jj];
        }
    }

    // ---- exp (unnormalized), row sum, write P(bf16) to sP
#pragma unroll
    for (int mi = 0; mi < 4; mi++) {
#pragma unroll
        for (int r = 0; r < 4; r++) {
            int row = wm + mi * 16 + quad * 4 + r;
            float rm = fmaxf(wmax[0][row], wmax[1][row]);
            float s = 0.f;
#pragma unroll
            for (int ni = 0; ni < 4; ni++) {
                float e = __expf(acc[mi][ni][r] - rm);
                acc[mi][ni][r] = e;
                s += e;
            }
            s += __shfl_xor(s, 1);
            s += __shfl_xor(s, 2);
            s += __shfl_xor(s, 4);
            s += __shfl_xor(s, 8);
            if (cl == 0) wsum[wn >> 6][row] = s;
#pragma unroll
            for (int ni = 0; ni < 4; ni++)
                sP[(size_t)row * 136 + wn + ni * 16 + cl] = f2b(acc[mi][ni][r]);
        }
    }
    __syncthreads();  // b2: wsum, sP, sVt ready

    if (tid < 128) sInv[tid] = 1.0f / (wsum[0][tid] + wsum[1][tid]);
    __syncthreads();  // b3: sInv ready

    // ---- write normalized att (fp32 output 1)
    size_t pbase = (size_t)hb * 128 * 128;
#pragma unroll
    for (int mi = 0; mi < 4; mi++) {
#pragma unroll
        for (int r = 0; r < 4; r++) {
            int row = wm + mi * 16 + quad * 4 + r;
            float iv = sInv[row];
#pragma unroll
            for (int ni = 0; ni < 4; ni++)
                att[pbase + (size_t)row * 128 + wn + ni * 16 + cl] =
                    acc[mi][ni][r] * iv;
        }
    }

    // ---- Phase 2: O = P @ V  (wave = rows [wave*32, wave*32+32), cols 0..95)
    int wm2 = wave * 32;
    f32x4 acc2[2][6];
#pragma unroll
    for (int i = 0; i < 2; i++)
#pragma unroll
        for (int j = 0; j < 6; j++) acc2[i][j] = (f32x4){0.f, 0.f, 0.f, 0.f};
#pragma unroll
    for (int ks = 0; ks < 4; ks++) {
        bf16x8 pa[2], vb[6];
#pragma unroll
        for (int mi2 = 0; mi2 < 2; mi2++)
            pa[mi2] = *(const bf16x8*)(sP + (size_t)(wm2 + mi2 * 16 + cl) * 136 + ks * 32 + quad * 8);
#pragma unroll
        for (int ni2 = 0; ni2 < 6; ni2++)
            vb[ni2] = *(const bf16x8*)(sVt + (size_t)(ni2 * 16 + cl) * 136 + ks * 32 + quad * 8);
#pragma unroll
        for (int mi2 = 0; mi2 < 2; mi2++)
#pragma unroll
            for (int ni2 = 0; ni2 < 6; ni2++)
                acc2[mi2][ni2] = __builtin_amdgcn_mfma_f32_16x16x32_bf16(
                    pa[mi2], vb[ni2], acc2[mi2][ni2], 0, 0, 0);
    }
    // epilogue: attout[row][h*96 + d] = O * inv[row]
#pragma unroll
    for (int mi2 = 0; mi2 < 2; mi2++) {
#pragma unroll
        for (int r = 0; r < 4; r++) {
            int row = wm2 + mi2 * 16 + quad * 4 + r;
            float iv = sInv[row];
#pragma unroll
            for (int ni2 = 0; ni2 < 6; ni2++) {
                int d = ni2 * 16 + cl;
                attout[rbase + (size_t)row * TDIM + d] =
                    f2b(acc2[mi2][ni2][r] * iv);
            }
        }
    }
}

extern "C" void kernel_launch(void* const* d_in, const int* in_sizes, int n_in,
                              void* d_out, int out_size, void* d_ws, size_t ws_size,
                              hipStream_t stream)
{
    const float* q     = (const float*)d_in[0];
    const float* k     = (const float*)d_in[1];
    const float* v     = (const float*)d_in[2];
    const float* ln1_g = (const float*)d_in[3];
    const float* ln1_b = (const float*)d_in[4];
    const float* wq    = (const float*)d_in[5];
    const float* wk    = (const float*)d_in[6];
    const float* wv    = (const float*)d_in[7];
    const float* wo    = (const float*)d_in[8];
    const float* wo_b  = (const float*)d_in[9];
    const float* ln2_g = (const float*)d_in[10];
    const float* ln2_b = (const float*)d_in[11];
    const float* w1    = (const float*)d_in[12];
    const float* b1    = (const float*)d_in[13];
    const float* w2    = (const float*)d_in[14];
    const float* b2    = (const float*)d_in[15];

    float* out0 = (float*)d_out;
    const size_t S = (size_t)NROWS * TDIM;  // 12,582,912
    float* att = out0 + S;                  // output 1: (2,64,8,128,128) fp32
    unsigned short* ws = (unsigned short*)d_ws;
    if (ws_size < 7 * S * sizeof(unsigned short)) return;  // need ~168 MB

    const size_t W = (size_t)TDIM * TDIM;   // 589,824
    const size_t W2 = (size_t)TDIM * THID;  // 2,359,296

    unsigned short* qn     = ws;          // slot0; later ln2y
    unsigned short* kn     = ws + S;      // slot1; later attout, then w1T/w2T
    unsigned short* vn     = ws + 2 * S;  // slot2; later y
    unsigned short* qh     = ws + 3 * S;  // slot3..5: qh/kh/vh; later hbuf (3..6)
    unsigned short* kh     = ws + 4 * S;
    unsigned short* vh     = ws + 5 * S;
    unsigned short* wqkvoT = ws + 6 * S;  // slot6: wq/wk/wv/wo ^T bf16 (dead at ffn1)
    unsigned short* attout = ws + S;
    unsigned short* y      = ws + 2 * S;
    unsigned short* ln2y   = ws;
    unsigned short* w1T    = ws + S;      // [3072][768], after attout dead
    unsigned short* w2T    = ws + S + W2; // [768][3072]
    unsigned short* hbuf   = ws + 3 * S;  // 16384 x 3072 (4S)

    dim3 blk(256);
    cvt_t_kernel<<<dim3(24, 24), blk, 0, stream>>>(wq, wqkvoT + 0 * W, TDIM, TDIM);
    cvt_t_kernel<<<dim3(24, 24), blk, 0, stream>>>(wk, wqkvoT + 1 * W, TDIM, TDIM);
    cvt_t_kernel<<<dim3(24, 24), blk, 0, stream>>>(wv, wqkvoT + 2 * W, TDIM, TDIM);
    cvt_t_kernel<<<dim3(24, 24), blk, 0, stream>>>(wo, wqkvoT + 3 * W, TDIM, TDIM);
    ln_kernel<true><<<dim3(NROWS, 3), blk, 0, stream>>>(
        q, k, v, ln1_g, ln1_b, qn, kn, vn);
    gemm_kernel<false, false, false, false><<<dim3(6, 128), blk, 0, stream>>>(
        qn, wqkvoT + 0 * W, nullptr, nullptr, qh, NROWS, TDIM, TDIM);
    gemm_kernel<false, false, false, false><<<dim3(6, 128), blk, 0, stream>>>(
        kn, wqkvoT + 1 * W, nullptr, nullptr, kh, NROWS, TDIM, TDIM);
    gemm_kernel<false, false, false, false><<<dim3(6, 128), blk, 0, stream>>>(
        vn, wqkvoT + 2 * W, nullptr, nullptr, vh, NROWS, TDIM, TDIM);
    attn_fused_kernel<<<dim3(1024), blk, 0, stream>>>(qh, kh, vh, att, attout);
    gemm_kernel<true, true, false, false><<<dim3(6, 128), blk, 0, stream>>>(
        attout, wqkvoT + 3 * W, wo_b, qn, y, NROWS, TDIM, TDIM);
    cvt_t_kernel<<<dim3(96, 24), blk, 0, stream>>>(w1, w1T, TDIM, THID);
    cvt_t_kernel<<<dim3(24, 96), blk, 0, stream>>>(w2, w2T, THID, TDIM);
    ln_kernel<false><<<dim3(NROWS, 1), blk, 0, stream>>>(
        y, y, y, ln2_g, ln2_b, ln2y, ln2y, ln2y);
    gemm_kernel<true, false, true, false><<<dim3(24, 128), blk, 0, stream>>>(
        ln2y, w1T, b1, nullptr, hbuf, NROWS, THID, TDIM);
    gemm_kernel<true, true, false, true><<<dim3(6, 128), blk, 0, stream>>>(
        hbuf, w2T, b2, y, out0, NROWS, TDIM, THID);
}